// Round 4
// baseline (67.385 us; speedup 1.0000x reference)
//
#include <hip/hip_runtime.h>

// Problem constants (from reference)
#define BATCH   4
#define N_VERTS 10000
#define N_FACES 20000
#define CUT_NUM 8
#define N_SAMP  80000
#define CC      128

typedef float f32x4 __attribute__((ext_vector_type(4)));

// out[b][v][k][c] = sum_j B[b][s][j] * x[b][F[I[s]][j]][c]  -  x[b][v][c]
//   where s = x_graph[v][k]
//
// One 32-lane group per output row (128 floats, f32x4 per lane).
// Block = 256 threads = 8 rows = all k for one v. Grid = (N_VERTS, BATCH).
__global__ __launch_bounds__(256) void fused_disk_features(
    const float* __restrict__ xf,   // [BATCH][N_VERTS][CC]
    const float* __restrict__ Bw,   // [BATCH][N_SAMP][3]
    const int*   __restrict__ xg,   // [N_VERTS][CUT_NUM]
    const int*   __restrict__ Fc,   // [N_FACES][3]
    const int*   __restrict__ Iv,   // [N_SAMP]
    float*       __restrict__ out)  // [BATCH][N_VERTS][CUT_NUM][CC]
{
    const int v    = blockIdx.x;
    const int b    = blockIdx.y;
    const int t    = threadIdx.x;
    const int k    = t >> 5;        // 0..7
    const int lane = t & 31;        // 0..31
    const int c0   = lane * 4;      // channel offset, float4 granularity

    const int s   = xg[v * CUT_NUM + k];
    const int fid = Iv[s];
    const int v0  = Fc[fid * 3 + 0];
    const int v1  = Fc[fid * 3 + 1];
    const int v2  = Fc[fid * 3 + 2];

    const float* bw = Bw + ((size_t)b * N_SAMP + s) * 3;
    const float w0 = bw[0];
    const float w1 = bw[1];
    const float w2 = bw[2];

    const float* xb = xf + (size_t)b * N_VERTS * CC;
    const f32x4 f0 = *(const f32x4*)(xb + (size_t)v0 * CC + c0);
    const f32x4 f1 = *(const f32x4*)(xb + (size_t)v1 * CC + c0);
    const f32x4 f2 = *(const f32x4*)(xb + (size_t)v2 * CC + c0);
    const f32x4 fx = *(const f32x4*)(xb + (size_t)v  * CC + c0);

    f32x4 r;
    r.x = fmaf(w0, f0.x, fmaf(w1, f1.x, fmaf(w2, f2.x, -fx.x)));
    r.y = fmaf(w0, f0.y, fmaf(w1, f1.y, fmaf(w2, f2.y, -fx.y)));
    r.z = fmaf(w0, f0.z, fmaf(w1, f1.z, fmaf(w2, f2.z, -fx.z)));
    r.w = fmaf(w0, f0.w, fmaf(w1, f1.w, fmaf(w2, f2.w, -fx.w)));

    f32x4* dst = (f32x4*)(out + ((((size_t)b * N_VERTS + v) * CUT_NUM + k) * CC + c0));
    __builtin_nontemporal_store(r, dst);
}

extern "C" void kernel_launch(void* const* d_in, const int* in_sizes, int n_in,
                              void* d_out, int out_size, void* d_ws, size_t ws_size,
                              hipStream_t stream) {
    const float* xf = (const float*)d_in[0];   // x_features (4,10000,128)
    const float* Bw = (const float*)d_in[1];   // B          (4,80000,3)
    const int*   xg = (const int*)  d_in[2];   // x_graph    (10000,8)
    const int*   Fc = (const int*)  d_in[3];   // F          (20000,3)
    const int*   Iv = (const int*)  d_in[4];   // I          (80000,)
    float*       out = (float*)d_out;          // (4,10000,8,128)

    dim3 grid(N_VERTS, BATCH);
    dim3 block(256);
    fused_disk_features<<<grid, block, 0, stream>>>(xf, Bw, xg, Fc, Iv, out);
}